// Round 19
// baseline (68.415 us; speedup 1.0000x reference)
//
#include <hip/hip_runtime.h>
#include <stdint.h>

// SSIM fused kernel v19, MI355X (gfx950).
// v18 post-mortem: neutral; DS pipe measured ~22% busy vs VALU 74.5% ->
// VALU is the sole binding pipe. The fp16 rb compression costs 56 cvt/thread
// (pass-2) + ~48 pack/item (pass-1) of pure VALU to relieve a pipe with 4x
// headroom. v19 stores rb in f32:
//  - rbA2[y][c] = float2(p,t), rbB2[y][c] = float2(pp,tt), rbC f32 (stride
//    76 for odd-row b128 alignment). Zero cvt/pack anywhere.
//  - LDS 40.4 KB -> still 4 blocks/CU (161792 <= 163840 B).
//  - Pass-2: 28 ds_read_b64 + 4 b128 (4-way aliasing on a 22%-busy pipe:
//    absorbed). Pass-1 stores: plain b64/b32, conflict-free.
//  - Stage-0 %74 hoisted out of the loop (increment mapping).
// All math f32 end-to-end (absmax 0 expected). Structure else = v18.

#define HH 512
#define WW 512
#define PLANES 48
#define TW 64
#define TH 16
#define RR 5
#define KK 11
#define HALO_W 74                  // halo cols c=0..73, global x = x0-5+c
#define TRP 28                     // padded rows per staged col (26 used)
#define RBW 74                     // rbA2/rbB2 row stride (float2)
#define RCW 76                     // rbC row stride (float, 16B row align)
#define NBLOCKS (PLANES * (WW / TW) * (HH / TH))  // 12288
#define NTHREADS 256
#define NITEMS1 (HALO_W * 2)      // 148 pass-1 items (col, 8-row group)
#define TOTAL_ELEMS (PLANES * HH * WW)

typedef float float2v __attribute__((ext_vector_type(2)));

constexpr float G_[KK] = {
    1.4867195147342977e-06f, 1.3383022576488537e-04f, 4.4318484119380075e-03f,
    5.3990966513188063e-02f, 2.4197072451914337e-01f, 3.9894228040143270e-01f,
    2.4197072451914337e-01f, 5.3990966513188063e-02f, 4.4318484119380075e-03f,
    1.3383022576488537e-04f, 1.4867195147342977e-06f};

__global__ __launch_bounds__(NTHREADS, 4) void ssim_tile_kernel(
    const float* __restrict__ pred, const float* __restrict__ targ,
    float* __restrict__ partial) {
  __shared__ __align__(16) float spT[HALO_W][TRP];   // 8.3 KB pred, col-major
  __shared__ __align__(16) float stT[HALO_W][TRP];   // 8.3 KB targ, col-major
  __shared__ __align__(16) float2v rbA2[TH][RBW];    // 9.25 KB (p, t) f32
  __shared__ __align__(16) float2v rbB2[TH][RBW];    // 9.25 KB (pp, tt) f32
  __shared__ __align__(16) float rbC[TH][RCW];       // 4.75 KB pt f32
  __shared__ float wsums[4];

  const int tid = threadIdx.x;
  const int bid = blockIdx.x;
  const int plane = bid >> 8;
  const int tile = bid & 255;
  const int x0 = (tile & 7) * TW;
  const int y0 = (tile >> 3) * TH;
  const float* pp = pred + (size_t)plane * (HH * WW);
  const float* tp = targ + (size_t)plane * (HH * WW);

  const bool interior = (x0 >= 64) && (x0 <= 384) && (y0 >= 16) && (y0 <= 480);

  // ---- Stage 0: transposed staging (v17 pattern); %74 hoisted ----
  {
    int c = tid % HALO_W;          // once per thread
    int rg = tid / HALO_W;
    if (interior) {
      while (rg < 7) {
        const float* pb = pp + (y0 - RR + 4 * rg) * WW + (x0 - RR + c);
        const float* tb = tp + (y0 - RR + 4 * rg) * WW + (x0 - RR + c);
        float4 pv, tv;
        pv.x = pb[0]; pv.y = pb[WW]; pv.z = pb[2 * WW]; pv.w = pb[3 * WW];
        tv.x = tb[0]; tv.y = tb[WW]; tv.z = tb[2 * WW]; tv.w = tb[3 * WW];
        *reinterpret_cast<float4*>(&spT[c][4 * rg]) = pv;
        *reinterpret_cast<float4*>(&stT[c][4 * rg]) = tv;
        c += 34; rg += 3;                      // advance 256 items
        if (c >= HALO_W) { c -= HALO_W; ++rg; }
      }
    } else {
      while (rg < 7) {
        const int gx = x0 - RR + c;
        const bool xok = (gx >= 0) && (gx < WW);
        float4 pv = make_float4(0.f, 0.f, 0.f, 0.f);
        float4 tv = pv;
        if (xok) {
#pragma unroll
          for (int w = 0; w < 4; ++w) {
            const int gy = y0 - RR + 4 * rg + w;
            if (gy >= 0 && gy < HH) {
              reinterpret_cast<float*>(&pv)[w] = pp[gy * WW + gx];
              reinterpret_cast<float*>(&tv)[w] = tp[gy * WW + gx];
            }
          }
        }
        *reinterpret_cast<float4*>(&spT[c][4 * rg]) = pv;
        *reinterpret_cast<float4*>(&stT[c][4 * rg]) = tv;
        c += 34; rg += 3;
        if (c >= HALO_W) { c -= HALO_W; ++rg; }
      }
    }
  }
  __syncthreads();

  // ---- Pass 1: VERTICAL conv, 8 outputs/item, one item/thread ----
  if (tid < NITEMS1) {
    const int c = (tid < HALO_W) ? tid : (tid - HALO_W);  // halo col 0..73
    const int g = (tid < HALO_W) ? 0 : 1;                  // row group
    const int yb = g * 8;            // output rows yb..yb+7; window yb..yb+17

    // 5 contiguous b128 per array: rows yb..yb+19 (18 used, 2 dead tail)
    float pv[20], tv[20];
#pragma unroll
    for (int h = 0; h < 5; ++h) {
      *reinterpret_cast<float4*>(&pv[4 * h]) =
          *reinterpret_cast<const float4*>(&spT[c][yb + 4 * h]);
      *reinterpret_cast<float4*>(&tv[4 * h]) =
          *reinterpret_cast<const float4*>(&stT[c][yb + 4 * h]);
    }

    // Scatter: window row q (0..17) feeds outputs j in [q-10, q] ∩ [0,7]
    // with weight G_[q-j].
    float2v s01[8] = {{0,0},{0,0},{0,0},{0,0},{0,0},{0,0},{0,0},{0,0}};
    float2v s23[8] = {{0,0},{0,0},{0,0},{0,0},{0,0},{0,0},{0,0},{0,0}};
    float s4[8] = {0,0,0,0,0,0,0,0};
#pragma unroll
    for (int q = 0; q < 18; ++q) {
      const float a = pv[q];
      const float b = tv[q];
      const float2v av = {a, b};
      const float2v sq = av * av;      // v_pk_mul_f32
      const float ab = a * b;
#pragma unroll
      for (int j = 0; j < 8; ++j) {
        if (q < j || q > j + 10) continue;
        const float w = G_[q - j];
        const float2v w2 = {w, w};
        s01[j] = __builtin_elementwise_fma(w2, av, s01[j]);  // v_pk_fma_f32
        s23[j] = __builtin_elementwise_fma(w2, sq, s23[j]);
        s4[j] = fmaf(w, ab, s4[j]);
      }
    }

#pragma unroll
    for (int j = 0; j < 8; ++j) {
      rbA2[yb + j][c] = s01[j];        // ds_write_b64, lanes->cols: clean
      rbB2[yb + j][c] = s23[j];        // ds_write_b64: clean
      rbC[yb + j][c] = s4[j];          // ds_write_b32: clean
    }
  }
  __syncthreads();

  // ---- Pass 2: HORIZONTAL conv (packed f32) + SSIM map; 256 items exact --
  float lsum = 0.f;
  {
    const int m = tid & 15;          // col group 0..15
    const int y = tid >> 4;          // output row 0..15
    const int cb = m << 2;           // window cols cb..cb+13 (outputs cb..cb+3)

    float2v fa[14], fb[14];
#pragma unroll
    for (int k = 0; k < 14; ++k) {
      fa[k] = rbA2[y][cb + k];         // ds_read_b64
      fb[k] = rbB2[y][cb + k];
    }
    float cv[16];
#pragma unroll
    for (int h = 0; h < 4; ++h) {
      *reinterpret_cast<float4*>(&cv[4 * h]) =
          *reinterpret_cast<const float4*>(&rbC[y][cb + 4 * h]);
    }

    float2v accA[4], accB[4];
    float sC[4];
#pragma unroll
    for (int j = 0; j < 4; ++j) {
      float2v a = {0, 0}, b = {0, 0};
      float c = 0.f;
#pragma unroll
      for (int k = 0; k < KK; ++k) {
        const float2v w2 = {G_[k], G_[k]};
        a = __builtin_elementwise_fma(w2, fa[j + k], a);
        b = __builtin_elementwise_fma(w2, fb[j + k], b);
        c = fmaf(G_[k], cv[j + k], c);
      }
      accA[j] = a; accB[j] = b; sC[j] = c;
    }

    const float C1 = 1.0e-4f;
    const float C2 = 9.0e-4f;
#pragma unroll
    for (int j = 0; j < 4; ++j) {
      const float mu_x = accA[j].x;
      const float mu_y = accA[j].y;
      const float2v sv = __builtin_elementwise_fma(-accA[j], accA[j], accB[j]);
      const float sxy = sC[j] - mu_x * mu_y;
      const float num = (2.f * mu_x * mu_y + C1) * (2.f * sxy + C2);
      const float den = (mu_x * mu_x + mu_y * mu_y + C1) *
                        (fmaf(sv.x, sv.x, fmaf(sv.y, sv.y, C2)));
      lsum = fmaf(num, __builtin_amdgcn_rcpf(den), lsum);
    }
  }

  // ---- Block reduction -> partial[bid] ----
#pragma unroll
  for (int off = 32; off > 0; off >>= 1) lsum += __shfl_xor(lsum, off, 64);
  if ((tid & 63) == 0) wsums[tid >> 6] = lsum;
  __syncthreads();
  if (tid == 0)
    partial[bid] = (wsums[0] + wsums[1]) + (wsums[2] + wsums[3]);
}

__global__ __launch_bounds__(1024) void ssim_reduce_kernel(
    const float* __restrict__ partial, float* __restrict__ out) {
  float s = 0.f;
  for (int i = threadIdx.x; i < NBLOCKS; i += 1024) s += partial[i];
#pragma unroll
  for (int off = 32; off > 0; off >>= 1) s += __shfl_xor(s, off, 64);
  __shared__ float ws[16];
  if ((threadIdx.x & 63) == 0) ws[threadIdx.x >> 6] = s;
  __syncthreads();
  if (threadIdx.x == 0) {
    float t = 0.f;
#pragma unroll
    for (int i = 0; i < 16; ++i) t += ws[i];
    out[0] = t * (1.0f / (float)TOTAL_ELEMS);
  }
}

extern "C" void kernel_launch(void* const* d_in, const int* in_sizes, int n_in,
                              void* d_out, int out_size, void* d_ws,
                              size_t ws_size, hipStream_t stream) {
  const float* pred = (const float*)d_in[0];
  const float* targ = (const float*)d_in[1];
  float* out = (float*)d_out;
  float* partial = (float*)d_ws;

  ssim_tile_kernel<<<NBLOCKS, NTHREADS, 0, stream>>>(pred, targ, partial);
  ssim_reduce_kernel<<<1, 1024, 0, stream>>>(partial, out);
}

// Round 20
// 59.187 us; speedup vs baseline: 1.1559x; 1.1559x over previous
//
#include <hip/hip_runtime.h>
#include <stdint.h>

// SSIM fused kernel v20, MI355X (gfx950).
// v18/v19 post-mortem: instruction cuts no longer convert (VALUBusy drops,
// time doesn't) -> latency/dependency-structure plateau, not issue-bound.
// v20 removes the stage-0 LDS round-trip entirely:
//  - Pass-1 threads load their column's 18 rows x 2 arrays DIRECTLY from
//    global into registers (transposed mapping: thread<->col c, consecutive
//    c = consecutive gx -> every row-read is a fully-coalesced 64-lane b32;
//    loads independent, issued upfront). Row overlap between the two
//    8-output groups = 1.38x, L1/L2-served.
//  - spT/stT (16.6 KB) + one barrier + ~2500 LDS instr/block deleted.
//    LDS 14.3 KB -> 5 blocks/CU (__launch_bounds__(256,5), VGPR cap 102).
//  - Pass-2 verbatim from v17 (best measured: 11 DS b128 reads, fp16-RTN
//    rbAB + f32 rbC). Full 11 taps, f32 accum everywhere.

#define HH 512
#define WW 512
#define PLANES 48
#define TW 64
#define TH 16
#define RR 5
#define KK 11
#define HALO_W 74                  // halo cols c=0..73, global x = x0-5+c
#define RBW 76                     // rb row stride
#define NBLOCKS (PLANES * (WW / TW) * (HH / TH))  // 12288
#define NTHREADS 256
#define NITEMS1 (HALO_W * 2)      // 148 pass-1 items (col, 8-row group)
#define TOTAL_ELEMS (PLANES * HH * WW)

typedef _Float16 half2v __attribute__((ext_vector_type(2)));
typedef float float2v __attribute__((ext_vector_type(2)));

constexpr float G_[KK] = {
    1.4867195147342977e-06f, 1.3383022576488537e-04f, 4.4318484119380075e-03f,
    5.3990966513188063e-02f, 2.4197072451914337e-01f, 3.9894228040143270e-01f,
    2.4197072451914337e-01f, 5.3990966513188063e-02f, 4.4318484119380075e-03f,
    1.3383022576488537e-04f, 1.4867195147342977e-06f};

__device__ __forceinline__ half2v u2h(uint32_t u) {
  return __builtin_bit_cast(half2v, u);
}
// RTN fp16 pack — unbiased (v4/v8 verified; RTZ pack is NOT safe, v7).
__device__ __forceinline__ uint32_t packrtn(float a, float b) {
  half2v h = {(_Float16)a, (_Float16)b};
  return __builtin_bit_cast(uint32_t, h);
}

__global__ __launch_bounds__(NTHREADS, 5) void ssim_tile_kernel(
    const float* __restrict__ pred, const float* __restrict__ targ,
    float* __restrict__ partial) {
  __shared__ __align__(16) uint2 rbAB[TH][RBW];     // 9.5 KB {pk(p,t),pk(pp,tt)}
  __shared__ __align__(16) float rbC[TH][RBW];      // 4.75 KB vconv_pt f32
  __shared__ float wsums[4];

  const int tid = threadIdx.x;
  const int bid = blockIdx.x;
  const int plane = bid >> 8;
  const int tile = bid & 255;
  const int x0 = (tile & 7) * TW;
  const int y0 = (tile >> 3) * TH;
  const float* pp = pred + (size_t)plane * (HH * WW);
  const float* tp = targ + (size_t)plane * (HH * WW);

  const bool interior = (x0 >= 64) && (x0 <= 384) && (y0 >= 16) && (y0 <= 480);

  // ---- Pass 1: fused global-load + VERTICAL conv, 8 outputs/item ----
  if (tid < NITEMS1) {
    const int c = (tid < HALO_W) ? tid : (tid - HALO_W);  // halo col 0..73
    const int g = (tid < HALO_W) ? 0 : 1;                  // row group
    const int yb = g * 8;            // output rows yb..yb+7; window yb..yb+17
    const int gx = x0 - RR + c;

    float pv[18], tv[18];
    if (interior) {
      const float* pc = pp + (size_t)(y0 - RR + yb) * WW + gx;
      const float* tc = tp + (size_t)(y0 - RR + yb) * WW + gx;
#pragma unroll
      for (int q = 0; q < 18; ++q) {
        pv[q] = pc[(size_t)q * WW];   // coalesced: consecutive c = consec gx
        tv[q] = tc[(size_t)q * WW];
      }
    } else {
      const bool xok = (gx >= 0) && (gx < WW);
#pragma unroll
      for (int q = 0; q < 18; ++q) {
        const int gy = y0 - RR + yb + q;
        const bool ok = xok && (gy >= 0) && (gy < HH);
        const int o = gy * WW + gx;
        pv[q] = ok ? pp[o] : 0.f;
        tv[q] = ok ? tp[o] : 0.f;
      }
    }

    // Scatter: window row q (0..17) feeds outputs j in [q-10, q] ∩ [0,7]
    // with weight G_[q-j].
    float2v s01[8] = {{0,0},{0,0},{0,0},{0,0},{0,0},{0,0},{0,0},{0,0}};
    float2v s23[8] = {{0,0},{0,0},{0,0},{0,0},{0,0},{0,0},{0,0},{0,0}};
    float s4[8] = {0,0,0,0,0,0,0,0};
#pragma unroll
    for (int q = 0; q < 18; ++q) {
      const float a = pv[q];
      const float b = tv[q];
      const float2v av = {a, b};
      const float2v sq = av * av;      // v_pk_mul_f32
      const float ab = a * b;
#pragma unroll
      for (int j = 0; j < 8; ++j) {
        if (q < j || q > j + 10) continue;
        const float w = G_[q - j];
        const float2v w2 = {w, w};
        s01[j] = __builtin_elementwise_fma(w2, av, s01[j]);  // v_pk_fma_f32
        s23[j] = __builtin_elementwise_fma(w2, sq, s23[j]);
        s4[j] = fmaf(w, ab, s4[j]);
      }
    }

#pragma unroll
    for (int j = 0; j < 8; ++j) {
      uint2 u;
      u.x = packrtn(s01[j].x, s01[j].y);
      u.y = packrtn(s23[j].x, s23[j].y);
      rbAB[yb + j][c] = u;             // ds_write_b64, lanes->cols: clean
      rbC[yb + j][c] = s4[j];          // ds_write_b32: clean
    }
  }
  __syncthreads();

  // ---- Pass 2: HORIZONTAL conv (packed f32) + SSIM map; 256 items exact --
  float lsum = 0.f;
  {
    const int m = tid & 15;          // col group 0..15
    const int y = tid >> 4;          // output row 0..15
    const int cb = m << 2;           // window cols cb..cb+13 (outputs cb..cb+3)

    uint2 qv[14];
#pragma unroll
    for (int h = 0; h < 7; ++h) {
      uint4 w = *reinterpret_cast<const uint4*>(&rbAB[y][cb + 2 * h]);
      qv[2*h]   = make_uint2(w.x, w.y);
      qv[2*h+1] = make_uint2(w.z, w.w);
    }
    float cv[16];
#pragma unroll
    for (int h = 0; h < 4; ++h) {
      *reinterpret_cast<float4*>(&cv[4*h]) =
          *reinterpret_cast<const float4*>(&rbC[y][cb + 4 * h]);
    }

    float2v fa[14], fb[14];
#pragma unroll
    for (int k = 0; k < 14; ++k) {
      half2v ha = u2h(qv[k].x), hb = u2h(qv[k].y);
      fa[k] = float2v{(float)ha.x, (float)ha.y};
      fb[k] = float2v{(float)hb.x, (float)hb.y};
    }

    float2v accA[4], accB[4];
    float sC[4];
#pragma unroll
    for (int j = 0; j < 4; ++j) {
      float2v a = {0, 0}, b = {0, 0};
      float c = 0.f;
#pragma unroll
      for (int k = 0; k < KK; ++k) {
        const float2v w2 = {G_[k], G_[k]};
        a = __builtin_elementwise_fma(w2, fa[j + k], a);
        b = __builtin_elementwise_fma(w2, fb[j + k], b);
        c = fmaf(G_[k], cv[j + k], c);
      }
      accA[j] = a; accB[j] = b; sC[j] = c;
    }

    const float C1 = 1.0e-4f;
    const float C2 = 9.0e-4f;
#pragma unroll
    for (int j = 0; j < 4; ++j) {
      const float mu_x = accA[j].x;
      const float mu_y = accA[j].y;
      const float2v sv = __builtin_elementwise_fma(-accA[j], accA[j], accB[j]);
      const float sxy = sC[j] - mu_x * mu_y;
      const float num = (2.f * mu_x * mu_y + C1) * (2.f * sxy + C2);
      const float den = (mu_x * mu_x + mu_y * mu_y + C1) *
                        (fmaf(sv.x, sv.x, fmaf(sv.y, sv.y, C2)));
      lsum = fmaf(num, __builtin_amdgcn_rcpf(den), lsum);
    }
  }

  // ---- Block reduction -> partial[bid] ----
#pragma unroll
  for (int off = 32; off > 0; off >>= 1) lsum += __shfl_xor(lsum, off, 64);
  if ((tid & 63) == 0) wsums[tid >> 6] = lsum;
  __syncthreads();
  if (tid == 0)
    partial[bid] = (wsums[0] + wsums[1]) + (wsums[2] + wsums[3]);
}

__global__ __launch_bounds__(1024) void ssim_reduce_kernel(
    const float* __restrict__ partial, float* __restrict__ out) {
  float s = 0.f;
  for (int i = threadIdx.x; i < NBLOCKS; i += 1024) s += partial[i];
#pragma unroll
  for (int off = 32; off > 0; off >>= 1) s += __shfl_xor(s, off, 64);
  __shared__ float ws[16];
  if ((threadIdx.x & 63) == 0) ws[threadIdx.x >> 6] = s;
  __syncthreads();
  if (threadIdx.x == 0) {
    float t = 0.f;
#pragma unroll
    for (int i = 0; i < 16; ++i) t += ws[i];
    out[0] = t * (1.0f / (float)TOTAL_ELEMS);
  }
}

extern "C" void kernel_launch(void* const* d_in, const int* in_sizes, int n_in,
                              void* d_out, int out_size, void* d_ws,
                              size_t ws_size, hipStream_t stream) {
  const float* pred = (const float*)d_in[0];
  const float* targ = (const float*)d_in[1];
  float* out = (float*)d_out;
  float* partial = (float*)d_ws;

  ssim_tile_kernel<<<NBLOCKS, NTHREADS, 0, stream>>>(pred, targ, partial);
  ssim_reduce_kernel<<<1, 1024, 0, stream>>>(partial, out);
}

// Round 21
// 56.090 us; speedup vs baseline: 1.2197x; 1.0552x over previous
//
#include <hip/hip_runtime.h>
#include <stdint.h>

// SSIM fused kernel v21, MI355X (gfx950).
// v20 post-mortem: BIG WIN (69.5->62.5us rocprof) - staging round-trip
// deleted; VALU again binding (76.5% busy, DS ~20%, occ 51%).
// v21: f32 rb storage (retry of v19's idea in the new regime):
//  - v20 pays 224 cvt + 48 pack wave-instr/block (~10% of VALU) to compress
//    rb to fp16, relieving a DS pipe with 4x headroom. Store f32 instead:
//    rbA2 = float2(p,t), rbB2 = float2(pp,tt), rbC = f32.
//  - Pass-2 reads: 28 ds_read_b64 + 4 b128 (v19's measured-conflict-free
//    pattern, 1.45e6). Zero cvt/pack anywhere; absmax 0 (pure f32).
//  - LDS 24.3 KB (<= 6 blocks/CU); pass-1 direct-global transposed loads
//    and everything else = v20.
// Pre-commitment: if >= 62us rocprof, declare latency-structure floor.

#define HH 512
#define WW 512
#define PLANES 48
#define TW 64
#define TH 16
#define RR 5
#define KK 11
#define HALO_W 74                  // halo cols c=0..73, global x = x0-5+c
#define RBW 74                     // rbA2/rbB2 row stride (float2)
#define RCW 76                     // rbC row stride (float, 16B row align)
#define NBLOCKS (PLANES * (WW / TW) * (HH / TH))  // 12288
#define NTHREADS 256
#define NITEMS1 (HALO_W * 2)      // 148 pass-1 items (col, 8-row group)
#define TOTAL_ELEMS (PLANES * HH * WW)

typedef float float2v __attribute__((ext_vector_type(2)));

constexpr float G_[KK] = {
    1.4867195147342977e-06f, 1.3383022576488537e-04f, 4.4318484119380075e-03f,
    5.3990966513188063e-02f, 2.4197072451914337e-01f, 3.9894228040143270e-01f,
    2.4197072451914337e-01f, 5.3990966513188063e-02f, 4.4318484119380075e-03f,
    1.3383022576488537e-04f, 1.4867195147342977e-06f};

__global__ __launch_bounds__(NTHREADS, 5) void ssim_tile_kernel(
    const float* __restrict__ pred, const float* __restrict__ targ,
    float* __restrict__ partial) {
  __shared__ __align__(16) float2v rbA2[TH][RBW];   // 9.25 KB (p, t) f32
  __shared__ __align__(16) float2v rbB2[TH][RBW];   // 9.25 KB (pp, tt) f32
  __shared__ __align__(16) float rbC[TH][RCW];      // 4.75 KB pt f32
  __shared__ float wsums[4];

  const int tid = threadIdx.x;
  const int bid = blockIdx.x;
  const int plane = bid >> 8;
  const int tile = bid & 255;
  const int x0 = (tile & 7) * TW;
  const int y0 = (tile >> 3) * TH;
  const float* pp = pred + (size_t)plane * (HH * WW);
  const float* tp = targ + (size_t)plane * (HH * WW);

  const bool interior = (x0 >= 64) && (x0 <= 384) && (y0 >= 16) && (y0 <= 480);

  // ---- Pass 1: fused global-load + VERTICAL conv, 8 outputs/item ----
  if (tid < NITEMS1) {
    const int c = (tid < HALO_W) ? tid : (tid - HALO_W);  // halo col 0..73
    const int g = (tid < HALO_W) ? 0 : 1;                  // row group
    const int yb = g * 8;            // output rows yb..yb+7; window yb..yb+17
    const int gx = x0 - RR + c;

    float pv[18], tv[18];
    if (interior) {
      const float* pc = pp + (size_t)(y0 - RR + yb) * WW + gx;
      const float* tc = tp + (size_t)(y0 - RR + yb) * WW + gx;
#pragma unroll
      for (int q = 0; q < 18; ++q) {
        pv[q] = pc[(size_t)q * WW];   // coalesced: consecutive c = consec gx
        tv[q] = tc[(size_t)q * WW];
      }
    } else {
      const bool xok = (gx >= 0) && (gx < WW);
#pragma unroll
      for (int q = 0; q < 18; ++q) {
        const int gy = y0 - RR + yb + q;
        const bool ok = xok && (gy >= 0) && (gy < HH);
        const int o = gy * WW + gx;
        pv[q] = ok ? pp[o] : 0.f;
        tv[q] = ok ? tp[o] : 0.f;
      }
    }

    // Scatter: window row q (0..17) feeds outputs j in [q-10, q] ∩ [0,7]
    // with weight G_[q-j].
    float2v s01[8] = {{0,0},{0,0},{0,0},{0,0},{0,0},{0,0},{0,0},{0,0}};
    float2v s23[8] = {{0,0},{0,0},{0,0},{0,0},{0,0},{0,0},{0,0},{0,0}};
    float s4[8] = {0,0,0,0,0,0,0,0};
#pragma unroll
    for (int q = 0; q < 18; ++q) {
      const float a = pv[q];
      const float b = tv[q];
      const float2v av = {a, b};
      const float2v sq = av * av;      // v_pk_mul_f32
      const float ab = a * b;
#pragma unroll
      for (int j = 0; j < 8; ++j) {
        if (q < j || q > j + 10) continue;
        const float w = G_[q - j];
        const float2v w2 = {w, w};
        s01[j] = __builtin_elementwise_fma(w2, av, s01[j]);  // v_pk_fma_f32
        s23[j] = __builtin_elementwise_fma(w2, sq, s23[j]);
        s4[j] = fmaf(w, ab, s4[j]);
      }
    }

#pragma unroll
    for (int j = 0; j < 8; ++j) {
      rbA2[yb + j][c] = s01[j];        // ds_write_b64, lanes->cols: clean
      rbB2[yb + j][c] = s23[j];        // ds_write_b64: clean
      rbC[yb + j][c] = s4[j];          // ds_write_b32: clean
    }
  }
  __syncthreads();

  // ---- Pass 2: HORIZONTAL conv (packed f32) + SSIM map; 256 items exact --
  float lsum = 0.f;
  {
    const int m = tid & 15;          // col group 0..15
    const int y = tid >> 4;          // output row 0..15
    const int cb = m << 2;           // window cols cb..cb+13 (outputs cb..cb+3)

    float2v fa[14], fb[14];
#pragma unroll
    for (int k = 0; k < 14; ++k) {
      fa[k] = rbA2[y][cb + k];         // ds_read_b64 (v19-measured clean)
      fb[k] = rbB2[y][cb + k];
    }
    float cv[16];
#pragma unroll
    for (int h = 0; h < 4; ++h) {
      *reinterpret_cast<float4*>(&cv[4 * h]) =
          *reinterpret_cast<const float4*>(&rbC[y][cb + 4 * h]);
    }

    float2v accA[4], accB[4];
    float sC[4];
#pragma unroll
    for (int j = 0; j < 4; ++j) {
      float2v a = {0, 0}, b = {0, 0};
      float c = 0.f;
#pragma unroll
      for (int k = 0; k < KK; ++k) {
        const float2v w2 = {G_[k], G_[k]};
        a = __builtin_elementwise_fma(w2, fa[j + k], a);
        b = __builtin_elementwise_fma(w2, fb[j + k], b);
        c = fmaf(G_[k], cv[j + k], c);
      }
      accA[j] = a; accB[j] = b; sC[j] = c;
    }

    const float C1 = 1.0e-4f;
    const float C2 = 9.0e-4f;
#pragma unroll
    for (int j = 0; j < 4; ++j) {
      const float mu_x = accA[j].x;
      const float mu_y = accA[j].y;
      const float2v sv = __builtin_elementwise_fma(-accA[j], accA[j], accB[j]);
      const float sxy = sC[j] - mu_x * mu_y;
      const float num = (2.f * mu_x * mu_y + C1) * (2.f * sxy + C2);
      const float den = (mu_x * mu_x + mu_y * mu_y + C1) *
                        (fmaf(sv.x, sv.x, fmaf(sv.y, sv.y, C2)));
      lsum = fmaf(num, __builtin_amdgcn_rcpf(den), lsum);
    }
  }

  // ---- Block reduction -> partial[bid] ----
#pragma unroll
  for (int off = 32; off > 0; off >>= 1) lsum += __shfl_xor(lsum, off, 64);
  if ((tid & 63) == 0) wsums[tid >> 6] = lsum;
  __syncthreads();
  if (tid == 0)
    partial[bid] = (wsums[0] + wsums[1]) + (wsums[2] + wsums[3]);
}

__global__ __launch_bounds__(1024) void ssim_reduce_kernel(
    const float* __restrict__ partial, float* __restrict__ out) {
  float s = 0.f;
  for (int i = threadIdx.x; i < NBLOCKS; i += 1024) s += partial[i];
#pragma unroll
  for (int off = 32; off > 0; off >>= 1) s += __shfl_xor(s, off, 64);
  __shared__ float ws[16];
  if ((threadIdx.x & 63) == 0) ws[threadIdx.x >> 6] = s;
  __syncthreads();
  if (threadIdx.x == 0) {
    float t = 0.f;
#pragma unroll
    for (int i = 0; i < 16; ++i) t += ws[i];
    out[0] = t * (1.0f / (float)TOTAL_ELEMS);
  }
}

extern "C" void kernel_launch(void* const* d_in, const int* in_sizes, int n_in,
                              void* d_out, int out_size, void* d_ws,
                              size_t ws_size, hipStream_t stream) {
  const float* pred = (const float*)d_in[0];
  const float* targ = (const float*)d_in[1];
  float* out = (float*)d_out;
  float* partial = (float*)d_ws;

  ssim_tile_kernel<<<NBLOCKS, NTHREADS, 0, stream>>>(pred, targ, partial);
  ssim_reduce_kernel<<<1, 1024, 0, stream>>>(partial, out);
}